// Round 1
// baseline (312.579 us; speedup 1.0000x reference)
//
#include <hip/hip_runtime.h>
#include <hip/hip_bf16.h>

typedef __bf16 bf16_t;
typedef __bf16 bf16x8 __attribute__((ext_vector_type(8)));
typedef float f32x4 __attribute__((ext_vector_type(4)));

#define SEQ_L 8192
#define DMODEL 1024
#define NHEAD 16
#define HDIM 64
static constexpr int MROWS = 2 * SEQ_L;  // B*L = 16384

// ---------------- async global->LDS (16B per lane) ----------------
__device__ __forceinline__ void async_cp16(const bf16_t* g, bf16_t* l) {
  __builtin_amdgcn_global_load_lds(
      (__attribute__((address_space(1))) void*)(void*)(g),
      (__attribute__((address_space(3))) void*)(void*)(l), 16, 0, 0);
}

// ---------------- f32 -> bf16 convert (vectorized) ----------------
__global__ __launch_bounds__(256) void f32_to_bf16_k(const float* __restrict__ in,
                                                     bf16_t* __restrict__ out, int n) {
  int i = (blockIdx.x * 256 + threadIdx.x) * 8;
  if (i >= n) return;
  float4 a = *(const float4*)(in + i);
  float4 b = *(const float4*)(in + i + 4);
  bf16x8 o;
  o[0] = (__bf16)a.x; o[1] = (__bf16)a.y; o[2] = (__bf16)a.z; o[3] = (__bf16)a.w;
  o[4] = (__bf16)b.x; o[5] = (__bf16)b.y; o[6] = (__bf16)b.z; o[7] = (__bf16)b.w;
  *(bf16x8*)(out + i) = o;
}

// ---------------- W (K x N f32) -> Wt (N x K bf16) ----------------
__global__ __launch_bounds__(256) void w_to_bt_k(
    const float* __restrict__ W0, const float* __restrict__ W1,
    const float* __restrict__ W2, const float* __restrict__ W3,
    bf16_t* __restrict__ T0, bf16_t* __restrict__ T1,
    bf16_t* __restrict__ T2, bf16_t* __restrict__ T3) {
  __shared__ float tile[32][33];
  const int z = blockIdx.z;
  const float* W = (z == 0) ? W0 : (z == 1) ? W1 : (z == 2) ? W2 : W3;
  bf16_t* T = (z == 0) ? T0 : (z == 1) ? T1 : (z == 2) ? T2 : T3;
  const int bx = blockIdx.x, by = blockIdx.y;
  const int tx = threadIdx.x, ty = threadIdx.y;  // 32 x 8
#pragma unroll
  for (int r = 0; r < 4; ++r)
    tile[ty + r * 8][tx] = W[(size_t)(by * 32 + ty + r * 8) * DMODEL + bx * 32 + tx];
  __syncthreads();
#pragma unroll
  for (int r = 0; r < 4; ++r)
    T[(size_t)(bx * 32 + ty + r * 8) * DMODEL + by * 32 + tx] = (bf16_t)tile[tx][ty + r * 8];
}

// ---------------- RoPE cos/sin table: tab[pos*32 + j] ----------------
__global__ __launch_bounds__(256) void rope_tab_k(float2* __restrict__ tab) {
  int i = blockIdx.x * 256 + threadIdx.x;  // pos*32 + j, 8192*32 entries
  int pos = i >> 5, j = i & 31;
  double freq = pow(10000.0, -(double)j / 32.0);
  double ang = (double)pos * freq;
  tab[i] = make_float2((float)cos(ang), (float)sin(ang));
}

// ---------------- bf16 GEMM: C(MxN) = A(MxK) @ Bt(NxK)^T + bias ----------------
// EPI 0: store bf16 (v-proj). EPI 1: bias+RoPE, store bf16 (q/k-proj). EPI 2: store f32 (final).
template <int EPI>
__global__ __launch_bounds__(256) void gemm_bt(const bf16_t* __restrict__ A,
                                               const bf16_t* __restrict__ Bt,
                                               const float* __restrict__ bias,
                                               const float2* __restrict__ rope,
                                               void* __restrict__ Cout,
                                               int M, int N, int K) {
  constexpr int BM = 128, BN = 128, BK = 32;
  __shared__ bf16_t As[BM * BK];
  __shared__ bf16_t Bs[BN * BK];
  const int tid = threadIdx.x;
  const int lane = tid & 63;
  const int wave = tid >> 6;
  const size_t row0 = (size_t)blockIdx.x * BM;
  const int col0 = blockIdx.y * BN;

  // staging: each thread owns 8 contiguous elements; 2 rounds (rows 0-63, 64-127) per operand
  const int srow = tid >> 2;          // 0..63
  const int scol = (tid & 3) * 8;     // 0,8,16,24
  const bf16_t* gA = A + (row0 + srow) * K + scol;
  const bf16_t* gB = Bt + (size_t)(col0 + srow) * K + scol;
  bf16_t* lA = As + tid * 8;
  bf16_t* lB = Bs + tid * 8;

  const int wr = (wave >> 1) * 64;  // wave row quadrant
  const int wc = (wave & 1) * 64;   // wave col quadrant (== one head for N-tiles)
  const int fr = lane & 15;
  const int fk = (lane >> 4) * 8;

  f32x4 acc[4][4] = {};

  for (int kt = 0; kt < K; kt += BK) {
    __syncthreads();
    async_cp16(gA, lA);
    async_cp16(gA + 64 * K, lA + 2048);
    async_cp16(gB, lB);
    async_cp16(gB + 64 * K, lB + 2048);
    gA += BK;
    gB += BK;
    __syncthreads();
    bf16x8 af[4], bg[4];
#pragma unroll
    for (int i = 0; i < 4; ++i) {
      af[i] = *(const bf16x8*)(As + (wr + i * 16 + fr) * BK + fk);
      bg[i] = *(const bf16x8*)(Bs + (wc + i * 16 + fr) * BK + fk);
    }
#pragma unroll
    for (int mi = 0; mi < 4; ++mi)
#pragma unroll
      for (int ni = 0; ni < 4; ++ni)
        acc[mi][ni] = __builtin_amdgcn_mfma_f32_16x16x32_bf16(af[mi], bg[ni], acc[mi][ni], 0, 0, 0);
  }

  // epilogue. C/D layout: col = lane&15, row = (lane>>4)*4 + reg
  const int lr = (lane >> 4) * 4;
  const int lc = lane & 15;
#pragma unroll
  for (int mi = 0; mi < 4; ++mi) {
#pragma unroll
    for (int i = 0; i < 4; ++i) {
      const size_t grow = row0 + wr + mi * 16 + lr + i;
      float vv[4];
#pragma unroll
      for (int ci = 0; ci < 4; ++ci)
        vv[ci] = acc[mi][ci][i] + bias[col0 + wc + ci * 16 + lc];
      if constexpr (EPI == 1) {
        // RoPE: within the wave's 64-col span (one head), d = ci*16+lc, j = d>>1,
        // partner d<32 ? d+32 (minus sin) : d-32 (plus sin)
        const int pos = (int)(grow & (size_t)(SEQ_L - 1));
        const float2* rp = rope + (size_t)pos * 32 + (lc >> 1);
        float rv[4];
#pragma unroll
        for (int ci = 0; ci < 4; ++ci) {
          float2 cs = rp[ci * 8];
          rv[ci] = (ci < 2) ? vv[ci] * cs.x - vv[ci + 2] * cs.y
                            : vv[ci] * cs.x + vv[ci - 2] * cs.y;
        }
#pragma unroll
        for (int ci = 0; ci < 4; ++ci) vv[ci] = rv[ci];
      }
      const size_t cbase = grow * (size_t)N + col0 + wc + lc;
      if constexpr (EPI == 2) {
        float* C = (float*)Cout;
#pragma unroll
        for (int ci = 0; ci < 4; ++ci) C[cbase + ci * 16] = vv[ci];
      } else {
        bf16_t* C = (bf16_t*)Cout;
#pragma unroll
        for (int ci = 0; ci < 4; ++ci) C[cbase + ci * 16] = (bf16_t)vv[ci];
      }
    }
  }
}

// ---------------- per-position head-mixing attention ----------------
// scores[h][e] = q[h,:]·k[e,:]/8 ; softmax over e (16 heads) ; out[h,:] = sum_e w*v[e,:]
// one thread per (position,row-head): t = row*16 + h
__global__ __launch_bounds__(256) void attn_heads_k(const bf16_t* __restrict__ qb,
                                                    const bf16_t* __restrict__ kb,
                                                    const bf16_t* __restrict__ vb,
                                                    bf16_t* __restrict__ ob) {
  const int t = blockIdx.x * 256 + threadIdx.x;
  const int row = t >> 4;
  const int h = t & 15;
  const size_t rbase = (size_t)row * DMODEL;

  float q[HDIM];
#pragma unroll
  for (int j = 0; j < 8; ++j) {
    bf16x8 v8 = *(const bf16x8*)(qb + rbase + h * HDIM + j * 8);
#pragma unroll
    for (int u = 0; u < 8; ++u) q[j * 8 + u] = (float)v8[u];
  }
  float s[NHEAD];
#pragma unroll
  for (int e = 0; e < NHEAD; ++e) {
    float a = 0.f;
#pragma unroll
    for (int j = 0; j < 8; ++j) {
      bf16x8 k8 = *(const bf16x8*)(kb + rbase + e * HDIM + j * 8);
#pragma unroll
      for (int u = 0; u < 8; ++u) a += q[j * 8 + u] * (float)k8[u];
    }
    s[e] = a * 0.125f;
  }
  float mx = s[0];
#pragma unroll
  for (int e = 1; e < NHEAD; ++e) mx = fmaxf(mx, s[e]);
  float sum = 0.f;
#pragma unroll
  for (int e = 0; e < NHEAD; ++e) {
    s[e] = __expf(s[e] - mx);
    sum += s[e];
  }
  const float inv = 1.f / sum;
  float o[HDIM] = {};
#pragma unroll
  for (int e = 0; e < NHEAD; ++e) {
    const float w = s[e] * inv;
#pragma unroll
    for (int j = 0; j < 8; ++j) {
      bf16x8 v8 = *(const bf16x8*)(vb + rbase + e * HDIM + j * 8);
#pragma unroll
      for (int u = 0; u < 8; ++u) o[j * 8 + u] += w * (float)v8[u];
    }
  }
#pragma unroll
  for (int j = 0; j < 8; ++j) {
    bf16x8 st;
#pragma unroll
    for (int u = 0; u < 8; ++u) st[u] = (__bf16)o[j * 8 + u];
    *(bf16x8*)(ob + rbase + h * HDIM + j * 8) = st;
  }
}

extern "C" void kernel_launch(void* const* d_in, const int* in_sizes, int n_in,
                              void* d_out, int out_size, void* d_ws, size_t ws_size,
                              hipStream_t stream) {
  const float* x = (const float*)d_in[0];
  const float* Wq = (const float*)d_in[1];
  const float* bq = (const float*)d_in[2];
  const float* Wk = (const float*)d_in[3];
  const float* bk = (const float*)d_in[4];
  const float* Wv = (const float*)d_in[5];
  const float* bv = (const float*)d_in[6];
  const float* Wo = (const float*)d_in[7];
  const float* bo = (const float*)d_in[8];

  const int M = MROWS, N = DMODEL, K = DMODEL;

  char* p = (char*)d_ws;
  bf16_t* xb = (bf16_t*)p;  p += (size_t)M * K * 2;       // 32 MB
  bf16_t* Wqt = (bf16_t*)p; p += (size_t)N * K * 2;       // 2 MB
  bf16_t* Wkt = (bf16_t*)p; p += (size_t)N * K * 2;
  bf16_t* Wvt = (bf16_t*)p; p += (size_t)N * K * 2;
  bf16_t* Wot = (bf16_t*)p; p += (size_t)N * K * 2;
  bf16_t* qb = (bf16_t*)p;  p += (size_t)M * N * 2;       // 32 MB each
  bf16_t* kb = (bf16_t*)p;  p += (size_t)M * N * 2;
  bf16_t* vb = (bf16_t*)p;  p += (size_t)M * N * 2;
  bf16_t* ab = (bf16_t*)p;  p += (size_t)M * N * 2;
  float2* rope = (float2*)p; p += (size_t)SEQ_L * 32 * sizeof(float2);  // 2 MB

  f32_to_bf16_k<<<(M * K) / (256 * 8), 256, 0, stream>>>(x, xb, M * K);
  w_to_bt_k<<<dim3(32, 32, 4), dim3(32, 8), 0, stream>>>(Wq, Wk, Wv, Wo, Wqt, Wkt, Wvt, Wot);
  rope_tab_k<<<(SEQ_L * 32) / 256, 256, 0, stream>>>(rope);

  dim3 gg(M / 128, N / 128);  // 128 x 8
  gemm_bt<1><<<gg, 256, 0, stream>>>(xb, Wqt, bq, rope, (void*)qb, M, N, K);
  gemm_bt<1><<<gg, 256, 0, stream>>>(xb, Wkt, bk, rope, (void*)kb, M, N, K);
  gemm_bt<0><<<gg, 256, 0, stream>>>(xb, Wvt, bv, nullptr, (void*)vb, M, N, K);
  attn_heads_k<<<(M * NHEAD) / 256, 256, 0, stream>>>(qb, kb, vb, ab);
  gemm_bt<2><<<gg, 256, 0, stream>>>(ab, Wot, bo, nullptr, d_out, M, N, K);
}

// Round 2
// 260.744 us; speedup vs baseline: 1.1988x; 1.1988x over previous
//
#include <hip/hip_runtime.h>
#include <hip/hip_bf16.h>

typedef __bf16 bf16_t;
typedef __bf16 bf16x8 __attribute__((ext_vector_type(8)));
typedef float f32x4 __attribute__((ext_vector_type(4)));

#define SEQ_L 8192
#define DMODEL 1024
#define NHEAD 16
#define HDIM 64
static constexpr int MROWS = 2 * SEQ_L;  // B*L = 16384

// ---------------- async global->LDS (16B per lane) ----------------
__device__ __forceinline__ void async_cp16(const bf16_t* g, bf16_t* l) {
  __builtin_amdgcn_global_load_lds(
      (__attribute__((address_space(1))) void*)(void*)(g),
      (__attribute__((address_space(3))) void*)(void*)(l), 16, 0, 0);
}

// ---------------- f32 -> bf16 convert (vectorized) ----------------
__global__ __launch_bounds__(256) void f32_to_bf16_k(const float* __restrict__ in,
                                                     bf16_t* __restrict__ out, int n) {
  int i = (blockIdx.x * 256 + threadIdx.x) * 8;
  if (i >= n) return;
  float4 a = *(const float4*)(in + i);
  float4 b = *(const float4*)(in + i + 4);
  bf16x8 o;
  o[0] = (__bf16)a.x; o[1] = (__bf16)a.y; o[2] = (__bf16)a.z; o[3] = (__bf16)a.w;
  o[4] = (__bf16)b.x; o[5] = (__bf16)b.y; o[6] = (__bf16)b.z; o[7] = (__bf16)b.w;
  *(bf16x8*)(out + i) = o;
}

// ---------------- W (K x N f32) -> Wt (N x K bf16) ----------------
__global__ __launch_bounds__(256) void w_to_bt_k(
    const float* __restrict__ W0, const float* __restrict__ W1,
    const float* __restrict__ W2, const float* __restrict__ W3,
    bf16_t* __restrict__ T0, bf16_t* __restrict__ T1,
    bf16_t* __restrict__ T2, bf16_t* __restrict__ T3) {
  __shared__ float tile[32][33];
  const int z = blockIdx.z;
  const float* W = (z == 0) ? W0 : (z == 1) ? W1 : (z == 2) ? W2 : W3;
  bf16_t* T = (z == 0) ? T0 : (z == 1) ? T1 : (z == 2) ? T2 : T3;
  const int bx = blockIdx.x, by = blockIdx.y;
  const int tx = threadIdx.x, ty = threadIdx.y;  // 32 x 8
#pragma unroll
  for (int r = 0; r < 4; ++r)
    tile[ty + r * 8][tx] = W[(size_t)(by * 32 + ty + r * 8) * DMODEL + bx * 32 + tx];
  __syncthreads();
#pragma unroll
  for (int r = 0; r < 4; ++r)
    T[(size_t)(bx * 32 + ty + r * 8) * DMODEL + by * 32 + tx] = (bf16_t)tile[tx][ty + r * 8];
}

// ---------------- RoPE cos/sin table: tab[pos*32 + j] ----------------
__global__ __launch_bounds__(256) void rope_tab_k(float2* __restrict__ tab) {
  int i = blockIdx.x * 256 + threadIdx.x;  // pos*32 + j, 8192*32 entries
  int pos = i >> 5, j = i & 31;
  double freq = pow(10000.0, -(double)j / 32.0);
  double ang = (double)pos * freq;
  tab[i] = make_float2((float)cos(ang), (float)sin(ang));
}

// ---------------- bf16 GEMM: C(MxN) = A(MxK) @ Bt(NxK)^T + bias ----------------
// 128x128 tile, BK=32, 4 waves, LDS double-buffered 2-phase prefetch (T3-minimum).
// MODE 0: fused QKV (N=3072): epilogue picks {q,k,v} output by col range, bias per
//         range, RoPE on q/k; bf16 out with per-output N=1024 stride.
// MODE 1: plain f32 out + bias (final O projection, N=1024).
template <int MODE>
__global__ __launch_bounds__(256) void gemm_bt(const bf16_t* __restrict__ A,
                                               const bf16_t* __restrict__ Bt,
                                               const float* __restrict__ b0,
                                               const float* __restrict__ b1,
                                               const float* __restrict__ b2,
                                               const float2* __restrict__ rope,
                                               void* __restrict__ O0,
                                               void* __restrict__ O1,
                                               void* __restrict__ O2,
                                               int M, int N, int K) {
  constexpr int BM = 128, BN = 128, BK = 32;
  __shared__ bf16_t As[2][BM * BK];
  __shared__ bf16_t Bs[2][BN * BK];
  const int tid = threadIdx.x;
  const int lane = tid & 63;
  const int wave = tid >> 6;
  const size_t row0 = (size_t)blockIdx.x * BM;
  const int col0 = blockIdx.y * BN;

  // staging: each thread owns 8 contiguous bf16 (16B); 2 rounds per operand
  const int srow = tid >> 2;       // 0..63
  const int scol = (tid & 3) * 8;  // 0,8,16,24
  const bf16_t* gA = A + (row0 + srow) * K + scol;
  const bf16_t* gB = Bt + (size_t)(col0 + srow) * K + scol;

  const int wr = (wave >> 1) * 64;  // wave row quadrant
  const int wc = (wave & 1) * 64;   // wave col quadrant (== one head span)
  const int fr = lane & 15;
  const int fk = (lane >> 4) * 8;

  f32x4 acc[4][4] = {};

  const int nk = K / BK;
  // prologue: stage tile 0 into buffer 0
  async_cp16(gA, &As[0][tid * 8]);
  async_cp16(gA + 64 * K, &As[0][2048 + tid * 8]);
  async_cp16(gB, &Bs[0][tid * 8]);
  async_cp16(gB + 64 * K, &Bs[0][2048 + tid * 8]);
  __syncthreads();

  int cur = 0;
  for (int kt = 0; kt < nk; ++kt) {
    if (kt + 1 < nk) {  // prefetch next tile into the other buffer
      const bf16_t* a = gA + (kt + 1) * BK;
      const bf16_t* b = gB + (kt + 1) * BK;
      const int nb = cur ^ 1;
      async_cp16(a, &As[nb][tid * 8]);
      async_cp16(a + 64 * K, &As[nb][2048 + tid * 8]);
      async_cp16(b, &Bs[nb][tid * 8]);
      async_cp16(b + 64 * K, &Bs[nb][2048 + tid * 8]);
    }
    bf16x8 af[4], bg[4];
#pragma unroll
    for (int i = 0; i < 4; ++i) {
      af[i] = *(const bf16x8*)(&As[cur][(wr + i * 16 + fr) * BK + fk]);
      bg[i] = *(const bf16x8*)(&Bs[cur][(wc + i * 16 + fr) * BK + fk]);
    }
#pragma unroll
    for (int mi = 0; mi < 4; ++mi)
#pragma unroll
      for (int ni = 0; ni < 4; ++ni)
        acc[mi][ni] = __builtin_amdgcn_mfma_f32_16x16x32_bf16(af[mi], bg[ni], acc[mi][ni], 0, 0, 0);
    __syncthreads();  // drains vmcnt (prefetch landed) + lgkmcnt, then barrier
    cur ^= 1;
  }

  // epilogue. C/D layout: col = lane&15, row = (lane>>4)*4 + reg
  const int which = (MODE == 0) ? (col0 >> 10) : 0;  // 0=q 1=k 2=v
  const float* bias = (MODE == 0) ? ((which == 0) ? b0 : (which == 1) ? b1 : b2) : b0;
  const int ocol0 = (MODE == 0) ? (col0 - (which << 10)) : col0;
  const bool do_rope = (MODE == 0) && (which < 2);

  const int lr = (lane >> 4) * 4;
  const int lc = lane & 15;
#pragma unroll
  for (int mi = 0; mi < 4; ++mi) {
#pragma unroll
    for (int i = 0; i < 4; ++i) {
      const size_t grow = row0 + wr + mi * 16 + lr + i;
      float vv[4];
#pragma unroll
      for (int ci = 0; ci < 4; ++ci)
        vv[ci] = acc[mi][ci][i] + bias[ocol0 + wc + ci * 16 + lc];
      if (do_rope) {
        // within the wave's 64-col span (one head), d = ci*16+lc, j = d>>1,
        // partner: d<32 ? d+32 (minus sin) : d-32 (plus sin)
        const int pos = (int)(grow & (size_t)(SEQ_L - 1));
        const float2* rp = rope + (size_t)pos * 32 + (lc >> 1);
        float rv[4];
#pragma unroll
        for (int ci = 0; ci < 4; ++ci) {
          float2 cs = rp[ci * 8];
          rv[ci] = (ci < 2) ? vv[ci] * cs.x - vv[ci + 2] * cs.y
                            : vv[ci] * cs.x + vv[ci - 2] * cs.y;
        }
#pragma unroll
        for (int ci = 0; ci < 4; ++ci) vv[ci] = rv[ci];
      }
      const size_t cbase = grow * (size_t)DMODEL + ocol0 + wc + lc;
      if constexpr (MODE == 1) {
        float* C = (float*)O0;
#pragma unroll
        for (int ci = 0; ci < 4; ++ci) C[cbase + ci * 16] = vv[ci];
      } else {
        bf16_t* C = (bf16_t*)((which == 0) ? O0 : (which == 1) ? O1 : O2);
#pragma unroll
        for (int ci = 0; ci < 4; ++ci) C[cbase + ci * 16] = (bf16_t)vv[ci];
      }
    }
  }
}

// ---------------- per-position head-mixing attention ----------------
// scores[h][e] = q[h,:]·k[e,:]/8 ; softmax over e (16 heads) ; out[h,:] = sum_e w*v[e,:]
__global__ __launch_bounds__(256) void attn_heads_k(const bf16_t* __restrict__ qb,
                                                    const bf16_t* __restrict__ kb,
                                                    const bf16_t* __restrict__ vb,
                                                    bf16_t* __restrict__ ob) {
  const int t = blockIdx.x * 256 + threadIdx.x;
  const int row = t >> 4;
  const int h = t & 15;
  const size_t rbase = (size_t)row * DMODEL;

  float q[HDIM];
#pragma unroll
  for (int j = 0; j < 8; ++j) {
    bf16x8 v8 = *(const bf16x8*)(qb + rbase + h * HDIM + j * 8);
#pragma unroll
    for (int u = 0; u < 8; ++u) q[j * 8 + u] = (float)v8[u];
  }
  float s[NHEAD];
#pragma unroll
  for (int e = 0; e < NHEAD; ++e) {
    float a = 0.f;
#pragma unroll
    for (int j = 0; j < 8; ++j) {
      bf16x8 k8 = *(const bf16x8*)(kb + rbase + e * HDIM + j * 8);
#pragma unroll
      for (int u = 0; u < 8; ++u) a += q[j * 8 + u] * (float)k8[u];
    }
    s[e] = a * 0.125f;
  }
  float mx = s[0];
#pragma unroll
  for (int e = 1; e < NHEAD; ++e) mx = fmaxf(mx, s[e]);
  float sum = 0.f;
#pragma unroll
  for (int e = 0; e < NHEAD; ++e) {
    s[e] = __expf(s[e] - mx);
    sum += s[e];
  }
  const float inv = 1.f / sum;
  float o[HDIM] = {};
#pragma unroll
  for (int e = 0; e < NHEAD; ++e) {
    const float w = s[e] * inv;
#pragma unroll
    for (int j = 0; j < 8; ++j) {
      bf16x8 v8 = *(const bf16x8*)(vb + rbase + e * HDIM + j * 8);
#pragma unroll
      for (int u = 0; u < 8; ++u) o[j * 8 + u] += w * (float)v8[u];
    }
  }
#pragma unroll
  for (int j = 0; j < 8; ++j) {
    bf16x8 st;
#pragma unroll
    for (int u = 0; u < 8; ++u) st[u] = (__bf16)o[j * 8 + u];
    *(bf16x8*)(ob + rbase + h * HDIM + j * 8) = st;
  }
}

extern "C" void kernel_launch(void* const* d_in, const int* in_sizes, int n_in,
                              void* d_out, int out_size, void* d_ws, size_t ws_size,
                              hipStream_t stream) {
  const float* x = (const float*)d_in[0];
  const float* Wq = (const float*)d_in[1];
  const float* bq = (const float*)d_in[2];
  const float* Wk = (const float*)d_in[3];
  const float* bk = (const float*)d_in[4];
  const float* Wv = (const float*)d_in[5];
  const float* bv = (const float*)d_in[6];
  const float* Wo = (const float*)d_in[7];
  const float* bo = (const float*)d_in[8];

  const int M = MROWS, N = DMODEL, K = DMODEL;

  char* p = (char*)d_ws;
  bf16_t* xb = (bf16_t*)p;    p += (size_t)M * K * 2;         // 32 MB
  bf16_t* Wqkvt = (bf16_t*)p; p += (size_t)3 * N * K * 2;     // 6 MB (q|k|v rows)
  bf16_t* Wot = (bf16_t*)p;   p += (size_t)N * K * 2;         // 2 MB
  bf16_t* qb = (bf16_t*)p;    p += (size_t)M * N * 2;         // 32 MB each
  bf16_t* kb = (bf16_t*)p;    p += (size_t)M * N * 2;
  bf16_t* vb = (bf16_t*)p;    p += (size_t)M * N * 2;
  bf16_t* ab = (bf16_t*)p;    p += (size_t)M * N * 2;
  float2* rope = (float2*)p;  p += (size_t)SEQ_L * 32 * sizeof(float2);  // 2 MB

  bf16_t* Wqt = Wqkvt;
  bf16_t* Wkt = Wqkvt + (size_t)N * K;
  bf16_t* Wvt = Wqkvt + (size_t)2 * N * K;

  f32_to_bf16_k<<<(M * K) / (256 * 8), 256, 0, stream>>>(x, xb, M * K);
  w_to_bt_k<<<dim3(32, 32, 4), dim3(32, 8), 0, stream>>>(Wq, Wk, Wv, Wo, Wqt, Wkt, Wvt, Wot);
  rope_tab_k<<<(SEQ_L * 32) / 256, 256, 0, stream>>>(rope);

  // fused QKV: C(16384 x 3072)
  gemm_bt<0><<<dim3(M / 128, (3 * N) / 128), 256, 0, stream>>>(
      xb, Wqkvt, bq, bk, bv, rope, (void*)qb, (void*)kb, (void*)vb, M, 3 * N, K);
  attn_heads_k<<<(M * NHEAD) / 256, 256, 0, stream>>>(qb, kb, vb, ab);
  gemm_bt<1><<<dim3(M / 128, N / 128), 256, 0, stream>>>(
      ab, Wot, bo, nullptr, nullptr, nullptr, d_out, nullptr, nullptr, M, N, K);
}

// Round 3
// 242.318 us; speedup vs baseline: 1.2900x; 1.0760x over previous
//
#include <hip/hip_runtime.h>
#include <hip/hip_bf16.h>

typedef __bf16 bf16_t;
typedef __bf16 bf16x8 __attribute__((ext_vector_type(8)));
typedef float f32x4 __attribute__((ext_vector_type(4)));

#define SEQ_L 8192
#define DMODEL 1024
#define NHEAD 16
#define HDIM 64
static constexpr int MROWS = 2 * SEQ_L;  // B*L = 16384

// ---------------- async global->LDS (16B per lane) ----------------
__device__ __forceinline__ void async_cp16(const bf16_t* g, bf16_t* l) {
  __builtin_amdgcn_global_load_lds(
      (__attribute__((address_space(1))) void*)(void*)(g),
      (__attribute__((address_space(3))) void*)(void*)(l), 16, 0, 0);
}
__device__ __forceinline__ void wg_barrier() { asm volatile("s_barrier" ::: "memory"); }

// ---------------- f32 -> bf16 convert (vectorized) ----------------
__global__ __launch_bounds__(256) void f32_to_bf16_k(const float* __restrict__ in,
                                                     bf16_t* __restrict__ out, int n) {
  int i = (blockIdx.x * 256 + threadIdx.x) * 8;
  if (i >= n) return;
  float4 a = *(const float4*)(in + i);
  float4 b = *(const float4*)(in + i + 4);
  bf16x8 o;
  o[0] = (__bf16)a.x; o[1] = (__bf16)a.y; o[2] = (__bf16)a.z; o[3] = (__bf16)a.w;
  o[4] = (__bf16)b.x; o[5] = (__bf16)b.y; o[6] = (__bf16)b.z; o[7] = (__bf16)b.w;
  *(bf16x8*)(out + i) = o;
}

// ---------------- W (K x N f32) -> Wt (N x K bf16) ----------------
__global__ __launch_bounds__(256) void w_to_bt_k(
    const float* __restrict__ W0, const float* __restrict__ W1,
    const float* __restrict__ W2, const float* __restrict__ W3,
    bf16_t* __restrict__ T0, bf16_t* __restrict__ T1,
    bf16_t* __restrict__ T2, bf16_t* __restrict__ T3) {
  __shared__ float tile[32][33];
  const int z = blockIdx.z;
  const float* W = (z == 0) ? W0 : (z == 1) ? W1 : (z == 2) ? W2 : W3;
  bf16_t* T = (z == 0) ? T0 : (z == 1) ? T1 : (z == 2) ? T2 : T3;
  const int bx = blockIdx.x, by = blockIdx.y;
  const int tx = threadIdx.x, ty = threadIdx.y;  // 32 x 8
#pragma unroll
  for (int r = 0; r < 4; ++r)
    tile[ty + r * 8][tx] = W[(size_t)(by * 32 + ty + r * 8) * DMODEL + bx * 32 + tx];
  __syncthreads();
#pragma unroll
  for (int r = 0; r < 4; ++r)
    T[(size_t)(bx * 32 + ty + r * 8) * DMODEL + by * 32 + tx] = (bf16_t)tile[tx][ty + r * 8];
}

// ---------------- RoPE cos/sin table: tab[pos*32 + j] ----------------
__global__ __launch_bounds__(256) void rope_tab_k(float2* __restrict__ tab) {
  int i = blockIdx.x * 256 + threadIdx.x;  // pos*32 + j
  int pos = i >> 5, j = i & 31;
  double freq = pow(10000.0, -(double)j / 32.0);
  double ang = (double)pos * freq;
  tab[i] = make_float2((float)cos(ang), (float)sin(ang));
}

// ---------------- 256x256 8-phase bf16 GEMM (T2+T3+T4+T5) ----------------
// C(M x N) = A(M x K) @ Bt(N x K)^T + bias, K = 1024, BK = 64, 8 waves (2M x 4N).
// Per K-tile: 4 phases, quadrant order (mh,nh) = (0,0),(0,1),(1,1),(1,0).
// Staging: 1 half-tile (2 x global_load_lds dwordx4 per thread) per phase:
//   phase0: A(m+1) h0 | phase1: A(m+1) h1 | phase2: B(m+2) h0 | phase3: B(m+2) h1
// Counted vmcnt(4) at K-tile boundary (leaves B(m+2) in flight). LDS st-swizzle:
// linear LDS dest, source chunk ^= row&7, same XOR on ds_read_b128 (rule #21).
// MODE 0: fused QKV (N=3072), bias per range, RoPE on q/k, bf16 outs (stride 1024).
// MODE 1: f32 out + bias (O projection, N=1024).
template <int MODE>
__global__ __launch_bounds__(512, 2) void gemm256(
    const bf16_t* __restrict__ A, const bf16_t* __restrict__ Bt,
    const float* __restrict__ b0, const float* __restrict__ b1,
    const float* __restrict__ b2, const float2* __restrict__ rope,
    void* __restrict__ O0, void* __restrict__ O1, void* __restrict__ O2) {
  constexpr int K = DMODEL;   // 1024
  constexpr int KT = K / 64;  // 16 K-tiles
  __shared__ bf16_t As_[2][256 * 64];
  __shared__ bf16_t Bs_[2][256 * 64];
  const int tid = threadIdx.x;
  const int lane = tid & 63;
  const int wave = tid >> 6;
  const int wm = wave >> 2;  // 0..1  (128-row half)
  const int wn = wave & 3;   // 0..3  (64-col span)
  const size_t row0 = (size_t)blockIdx.x * 256;
  const int col0 = blockIdx.y * 256;
  const int fr = lane & 15;
  const int fkb = (lane >> 4) * 16;  // k-fragment byte offset within 64B k-half

  // staging precompute: thread covers rows srow(+64 for 2nd cp), swizzled chunk
  const int srow = tid >> 3;                        // 0..63
  const int schunk = (tid & 7) ^ ((tid >> 3) & 7);  // pre-swizzled source chunk
  const bf16_t* gA = A + (row0 + srow) * K + schunk * 8;
  const bf16_t* gB = Bt + ((size_t)col0 + srow) * K + schunk * 8;

#define STAGE_A(j, h)                                  \
  do {                                                 \
    const bf16_t* _g = gA + ((h)*128) * K + (j)*64;    \
    bf16_t* _l = &As_[(j)&1][(h)*8192 + tid * 8];      \
    async_cp16(_g, _l);                                \
    async_cp16(_g + 64 * K, _l + 4096);                \
  } while (0)
#define STAGE_B(j, h)                                  \
  do {                                                 \
    const bf16_t* _g = gB + ((h)*128) * K + (j)*64;    \
    bf16_t* _l = &Bs_[(j)&1][(h)*8192 + tid * 8];      \
    async_cp16(_g, _l);                                \
    async_cp16(_g + 64 * K, _l + 4096);                \
  } while (0)
#define RD(base, row, kh)                                                    \
  (*(const bf16x8*)((const char*)(base) +                                    \
                    (((row)*128 + ((kh)*64 + fkb)) ^ (((row)&7) << 4))))

  f32x4 acc[8][4] = {};
  bf16x8 af[4][2], bf0[2][2], bf1[2][2];

  // prologue: A(0) h0/h1, B(0) h0/h1 must land; B(1) h0/h1 stays in flight
  STAGE_A(0, 0); STAGE_A(0, 1);
  STAGE_B(0, 0); STAGE_B(0, 1);
  STAGE_B(1, 0); STAGE_B(1, 1);
  asm volatile("s_waitcnt vmcnt(4)" ::: "memory");
  wg_barrier();

  for (int m = 0; m < KT; ++m) {
    const bf16_t* Ac = &As_[m & 1][0];
    const bf16_t* Bc = &Bs_[m & 1][0];
    // ---- phase 0: quadrant (mh=0, nh=0) ----
#pragma unroll
    for (int f = 0; f < 4; ++f) {
      const int r = wm * 128 + f * 16 + fr;
      af[f][0] = RD(Ac, r, 0);
      af[f][1] = RD(Ac, r, 1);
    }
#pragma unroll
    for (int f = 0; f < 2; ++f) {
      const int r = wn * 64 + f * 16 + fr;
      bf0[f][0] = RD(Bc, r, 0);
      bf0[f][1] = RD(Bc, r, 1);
    }
    if (m + 1 < KT) STAGE_A(m + 1, 0);
    wg_barrier();
    __builtin_amdgcn_s_setprio(1);
#pragma unroll
    for (int f = 0; f < 4; ++f)
#pragma unroll
      for (int n = 0; n < 2; ++n)
#pragma unroll
        for (int kh = 0; kh < 2; ++kh)
          acc[f][n] = __builtin_amdgcn_mfma_f32_16x16x32_bf16(af[f][kh], bf0[n][kh], acc[f][n], 0, 0, 0);
    __builtin_amdgcn_s_setprio(0);
    wg_barrier();
    // ---- phase 1: quadrant (mh=0, nh=1) ----
#pragma unroll
    for (int f = 0; f < 2; ++f) {
      const int r = wn * 64 + (2 + f) * 16 + fr;
      bf1[f][0] = RD(Bc, r, 0);
      bf1[f][1] = RD(Bc, r, 1);
    }
    if (m + 1 < KT) STAGE_A(m + 1, 1);
    wg_barrier();
    __builtin_amdgcn_s_setprio(1);
#pragma unroll
    for (int f = 0; f < 4; ++f)
#pragma unroll
      for (int n = 0; n < 2; ++n)
#pragma unroll
        for (int kh = 0; kh < 2; ++kh)
          acc[f][2 + n] = __builtin_amdgcn_mfma_f32_16x16x32_bf16(af[f][kh], bf1[n][kh], acc[f][2 + n], 0, 0, 0);
    __builtin_amdgcn_s_setprio(0);
    wg_barrier();
    // ---- phase 2: quadrant (mh=1, nh=1); A-frags 4..7 overwrite af ----
#pragma unroll
    for (int f = 0; f < 4; ++f) {
      const int r = wm * 128 + (4 + f) * 16 + fr;
      af[f][0] = RD(Ac, r, 0);
      af[f][1] = RD(Ac, r, 1);
    }
    if (m + 2 < KT) STAGE_B(m + 2, 0);
    wg_barrier();
    __builtin_amdgcn_s_setprio(1);
#pragma unroll
    for (int f = 0; f < 4; ++f)
#pragma unroll
      for (int n = 0; n < 2; ++n)
#pragma unroll
        for (int kh = 0; kh < 2; ++kh)
          acc[4 + f][2 + n] = __builtin_amdgcn_mfma_f32_16x16x32_bf16(af[f][kh], bf1[n][kh], acc[4 + f][2 + n], 0, 0, 0);
    __builtin_amdgcn_s_setprio(0);
    wg_barrier();
    // ---- phase 3: quadrant (mh=1, nh=0); no ds_reads (bf0 kept in regs) ----
    if (m + 2 < KT) {
      STAGE_B(m + 2, 1);
      asm volatile("s_waitcnt vmcnt(4)" ::: "memory");  // A(m+1), B(m+1) landed
    } else if (m + 1 < KT) {
      asm volatile("s_waitcnt vmcnt(0)" ::: "memory");  // drain for last K-tile
    }
    wg_barrier();
    __builtin_amdgcn_s_setprio(1);
#pragma unroll
    for (int f = 0; f < 4; ++f)
#pragma unroll
      for (int n = 0; n < 2; ++n)
#pragma unroll
        for (int kh = 0; kh < 2; ++kh)
          acc[4 + f][n] = __builtin_amdgcn_mfma_f32_16x16x32_bf16(af[f][kh], bf0[n][kh], acc[4 + f][n], 0, 0, 0);
    __builtin_amdgcn_s_setprio(0);
    wg_barrier();
  }
#undef STAGE_A
#undef STAGE_B
#undef RD

  // ---- epilogue. C/D layout: col = lane&15, row = (lane>>4)*4 + reg ----
  const int lr = (lane >> 4) * 4;
  const int lc = lane & 15;
  const int gcol = col0 + wn * 64;  // aligned to one head (64)
  int which = 0;
  const float* bias = b0;
  int ocol = gcol;
  if constexpr (MODE == 0) {
    which = gcol >> 10;
    bias = (which == 0) ? b0 : (which == 1) ? b1 : b2;
    ocol = gcol - (which << 10);
  }
  const bool do_rope = (MODE == 0) && (which < 2);
  bf16_t* Cb = nullptr;
  float* Cf = nullptr;
  if constexpr (MODE == 0)
    Cb = (bf16_t*)((which == 0) ? O0 : (which == 1) ? O1 : O2);
  else
    Cf = (float*)O0;

#pragma unroll
  for (int mf = 0; mf < 8; ++mf) {
#pragma unroll
    for (int i = 0; i < 4; ++i) {
      const size_t grow = row0 + wm * 128 + mf * 16 + lr + i;
      float vv[4];
#pragma unroll
      for (int n = 0; n < 4; ++n) vv[n] = acc[mf][n][i] + bias[ocol + n * 16 + lc];
      if (do_rope) {
        // d(in-head) = n*16+lc; j = d>>1; partner d<32 ? d+32 (-sin) : d-32 (+sin)
        const int pos = (int)(grow & (size_t)(SEQ_L - 1));
        const float2* rp = rope + (size_t)pos * 32 + (lc >> 1);
        float rv[4];
#pragma unroll
        for (int n = 0; n < 4; ++n) {
          float2 cs = rp[n * 8];
          rv[n] = (n < 2) ? vv[n] * cs.x - vv[n + 2] * cs.y
                          : vv[n] * cs.x + vv[n - 2] * cs.y;
        }
#pragma unroll
        for (int n = 0; n < 4; ++n) vv[n] = rv[n];
      }
      const size_t cbase = grow * (size_t)DMODEL + ocol + lc;
      if constexpr (MODE == 1) {
#pragma unroll
        for (int n = 0; n < 4; ++n) Cf[cbase + n * 16] = vv[n];
      } else {
#pragma unroll
        for (int n = 0; n < 4; ++n) Cb[cbase + n * 16] = (bf16_t)vv[n];
      }
    }
  }
}

// ---------------- per-position head-mixing attention ----------------
__global__ __launch_bounds__(256) void attn_heads_k(const bf16_t* __restrict__ qb,
                                                    const bf16_t* __restrict__ kb,
                                                    const bf16_t* __restrict__ vb,
                                                    bf16_t* __restrict__ ob) {
  const int t = blockIdx.x * 256 + threadIdx.x;
  const int row = t >> 4;
  const int h = t & 15;
  const size_t rbase = (size_t)row * DMODEL;

  float q[HDIM];
#pragma unroll
  for (int j = 0; j < 8; ++j) {
    bf16x8 v8 = *(const bf16x8*)(qb + rbase + h * HDIM + j * 8);
#pragma unroll
    for (int u = 0; u < 8; ++u) q[j * 8 + u] = (float)v8[u];
  }
  float s[NHEAD];
#pragma unroll
  for (int e = 0; e < NHEAD; ++e) {
    float a = 0.f;
#pragma unroll
    for (int j = 0; j < 8; ++j) {
      bf16x8 k8 = *(const bf16x8*)(kb + rbase + e * HDIM + j * 8);
#pragma unroll
      for (int u = 0; u < 8; ++u) a += q[j * 8 + u] * (float)k8[u];
    }
    s[e] = a * 0.125f;
  }
  float mx = s[0];
#pragma unroll
  for (int e = 1; e < NHEAD; ++e) mx = fmaxf(mx, s[e]);
  float sum = 0.f;
#pragma unroll
  for (int e = 0; e < NHEAD; ++e) {
    s[e] = __expf(s[e] - mx);
    sum += s[e];
  }
  const float inv = 1.f / sum;
  float o[HDIM] = {};
#pragma unroll
  for (int e = 0; e < NHEAD; ++e) {
    const float w = s[e] * inv;
#pragma unroll
    for (int j = 0; j < 8; ++j) {
      bf16x8 v8 = *(const bf16x8*)(vb + rbase + e * HDIM + j * 8);
#pragma unroll
      for (int u = 0; u < 8; ++u) o[j * 8 + u] += w * (float)v8[u];
    }
  }
#pragma unroll
  for (int j = 0; j < 8; ++j) {
    bf16x8 st;
#pragma unroll
    for (int u = 0; u < 8; ++u) st[u] = (__bf16)o[j * 8 + u];
    *(bf16x8*)(ob + rbase + h * HDIM + j * 8) = st;
  }
}

extern "C" void kernel_launch(void* const* d_in, const int* in_sizes, int n_in,
                              void* d_out, int out_size, void* d_ws, size_t ws_size,
                              hipStream_t stream) {
  const float* x = (const float*)d_in[0];
  const float* Wq = (const float*)d_in[1];
  const float* bq = (const float*)d_in[2];
  const float* Wk = (const float*)d_in[3];
  const float* bk = (const float*)d_in[4];
  const float* Wv = (const float*)d_in[5];
  const float* bv = (const float*)d_in[6];
  const float* Wo = (const float*)d_in[7];
  const float* bo = (const float*)d_in[8];

  const int M = MROWS, N = DMODEL, K = DMODEL;

  char* p = (char*)d_ws;
  bf16_t* xb = (bf16_t*)p;    p += (size_t)M * K * 2;      // 32 MB
  bf16_t* Wqkvt = (bf16_t*)p; p += (size_t)3 * N * K * 2;  // 6 MB (q|k|v rows)
  bf16_t* Wot = (bf16_t*)p;   p += (size_t)N * K * 2;      // 2 MB
  bf16_t* qb = (bf16_t*)p;    p += (size_t)M * N * 2;      // 32 MB each
  bf16_t* kb = (bf16_t*)p;    p += (size_t)M * N * 2;
  bf16_t* vb = (bf16_t*)p;    p += (size_t)M * N * 2;
  bf16_t* ab = (bf16_t*)p;    p += (size_t)M * N * 2;
  float2* rope = (float2*)p;  p += (size_t)SEQ_L * 32 * sizeof(float2);  // 2 MB

  bf16_t* Wqt = Wqkvt;
  bf16_t* Wkt = Wqkvt + (size_t)N * K;
  bf16_t* Wvt = Wqkvt + (size_t)2 * N * K;

  f32_to_bf16_k<<<(M * K) / (256 * 8), 256, 0, stream>>>(x, xb, M * K);
  w_to_bt_k<<<dim3(32, 32, 4), dim3(32, 8), 0, stream>>>(Wq, Wk, Wv, Wo, Wqt, Wkt, Wvt, Wot);
  rope_tab_k<<<(SEQ_L * 32) / 256, 256, 0, stream>>>(rope);

  // fused QKV: C(16384 x 3072), 64 x 12 blocks of 256^2
  gemm256<0><<<dim3(M / 256, (3 * N) / 256), 512, 0, stream>>>(
      xb, Wqkvt, bq, bk, bv, rope, (void*)qb, (void*)kb, (void*)vb);
  attn_heads_k<<<(M * NHEAD) / 256, 256, 0, stream>>>(qb, kb, vb, ab);
  gemm256<1><<<dim3(M / 256, N / 256), 512, 0, stream>>>(
      ab, Wot, bo, nullptr, nullptr, nullptr, d_out, nullptr, nullptr);
}